// Round 1
// baseline (1902.460 us; speedup 1.0000x reference)
//
#include <hip/hip_runtime.h>

#define NN 50000
#define NE 800000
#define BN_EPS 1e-5f
#define SCAN_T 256
#define SCAN_NB ((NN + SCAN_T - 1) / SCAN_T) // 196

using bf16x8 = __attribute__((ext_vector_type(8))) __bf16;
using floatx4 = __attribute__((ext_vector_type(4))) float;

#define MFMA16(a, b, c) __builtin_amdgcn_mfma_f32_16x16x32_bf16(a, b, c, 0, 0, 0)

// W: row-major [K][ncols] f32. B-frag for 16x16x32: lane holds
// B[k = (lane>>4)*8 + j + kb*32][col = ct*16 + (lane&15)], j=0..7.
__device__ __forceinline__ bf16x8 load_wfrag(const float* W, int ncols, int kb, int ct, int lane) {
  int col = ct * 16 + (lane & 15);
  int k0 = kb * 32 + ((lane >> 4) << 3);
  bf16x8 f;
#pragma unroll
  for (int j = 0; j < 8; ++j) f[j] = (__bf16)W[(k0 + j) * ncols + col];
  return f;
}

// ---------------- setup ----------------
__global__ void k_setup(const int* __restrict__ nodes, const float* __restrict__ emb,
                        float* __restrict__ x, int* __restrict__ cnt_d, int* __restrict__ cnt_s) {
  int tid = blockIdx.x * blockDim.x + threadIdx.x;
  int stride = gridDim.x * blockDim.x;
  for (int idx = tid; idx < NN * 64; idx += stride)
    x[idx] = emb[nodes[idx >> 6] * 64 + (idx & 63)];
  for (int n = tid; n < NN; n += stride) { cnt_d[n] = 0; cnt_s[n] = 0; }
}

__global__ void k_hist(const int* __restrict__ src, const int* __restrict__ dst,
                       int* __restrict__ cnt_d, int* __restrict__ cnt_s) {
  int tid = blockIdx.x * blockDim.x + threadIdx.x;
  int stride = gridDim.x * blockDim.x;
  for (int e = tid; e < NE; e += stride) {
    atomicAdd(&cnt_d[dst[e]], 1);
    atomicAdd(&cnt_s[src[e]], 1);
  }
}

__global__ void k_scan1(const int* __restrict__ cnt_d, const int* __restrict__ cnt_s,
                        int* __restrict__ off_d, int* __restrict__ off_s, int* __restrict__ btot) {
  const int* cnt = blockIdx.y ? cnt_s : cnt_d;
  int* off = blockIdx.y ? off_s : off_d;
  __shared__ int sm[SCAN_T];
  int i = blockIdx.x * SCAN_T + threadIdx.x;
  int v = (i < NN) ? cnt[i] : 0;
  sm[threadIdx.x] = v;
  __syncthreads();
  for (int o = 1; o < SCAN_T; o <<= 1) {
    int u = (threadIdx.x >= o) ? sm[threadIdx.x - o] : 0;
    __syncthreads();
    sm[threadIdx.x] += u;
    __syncthreads();
  }
  if (i < NN) off[i] = sm[threadIdx.x]; // in-block inclusive (temp)
  if (threadIdx.x == SCAN_T - 1) btot[blockIdx.y * SCAN_NB + blockIdx.x] = sm[SCAN_T - 1];
}

__global__ void k_scan2(int* __restrict__ btot) {
  __shared__ int sm[SCAN_T];
  int t = threadIdx.x;
  for (int y = 0; y < 2; ++y) {
    int v = (t < SCAN_NB) ? btot[y * SCAN_NB + t] : 0;
    sm[t] = v;
    __syncthreads();
    for (int o = 1; o < SCAN_T; o <<= 1) {
      int u = (t >= o) ? sm[t - o] : 0;
      __syncthreads();
      sm[t] += u;
      __syncthreads();
    }
    if (t < SCAN_NB) btot[y * SCAN_NB + t] = sm[t] - v; // exclusive
    __syncthreads();
  }
}

__global__ void k_scan3(const int* __restrict__ cnt_d, const int* __restrict__ cnt_s,
                        int* __restrict__ off_d, int* __restrict__ off_s,
                        const int* __restrict__ btot, int* __restrict__ cur_d,
                        int* __restrict__ cur_s, float* __restrict__ dinv_d,
                        float* __restrict__ dinv_s) {
  const int* cnt = blockIdx.y ? cnt_s : cnt_d;
  int* off = blockIdx.y ? off_s : off_d;
  int* cur = blockIdx.y ? cur_s : cur_d;
  float* dinv = blockIdx.y ? dinv_s : dinv_d;
  int i = blockIdx.x * SCAN_T + threadIdx.x;
  if (i < NN) {
    int incl = off[i];
    int c = cnt[i];
    int o = incl - c + btot[blockIdx.y * SCAN_NB + blockIdx.x];
    off[i] = o;
    cur[i] = o;
    dinv[i] = c > 0 ? 1.0f / (float)c : 0.f;
  }
  if (i == NN - 1) off[NN] = NE;
}

__global__ void k_fill(const int* __restrict__ src, const int* __restrict__ dst,
                       int* __restrict__ cur_d, int* __restrict__ cur_s,
                       int* __restrict__ el_d, int* __restrict__ el_s) {
  int tid = blockIdx.x * blockDim.x + threadIdx.x;
  int stride = gridDim.x * blockDim.x;
  for (int e = tid; e < NE; e += stride) {
    int p = atomicAdd(&cur_d[dst[e]], 1);
    el_d[p] = e;
    int q = atomicAdd(&cur_s[src[e]], 1);
    el_s[q] = e;
  }
}

// ---------------- per-aggregation kernels ----------------
// KA: A = x@W1[0:64] + b1 ; B = x@W1[64:128]   (bf16 MFMA, f32 out). Also zeros stats.
__global__ void __launch_bounds__(256) k_node_xform(
    const float* __restrict__ x, const float* __restrict__ W1, const float* __restrict__ b1,
    float* __restrict__ Ab, float* __restrict__ Bb, float* __restrict__ stats) {
  const int lane = threadIdx.x & 63;
  const int wid = threadIdx.x >> 6;
  __shared__ alignas(16) __bf16 xb[4][16 * 72];
  if (blockIdx.x == 0 && threadIdx.x < 256) stats[threadIdx.x] = 0.f;
  bf16x8 wfa[4][2], wfb[4][2];
#pragma unroll
  for (int ct = 0; ct < 4; ++ct)
#pragma unroll
    for (int kb = 0; kb < 2; ++kb) {
      wfa[ct][kb] = load_wfrag(W1, 64, kb, ct, lane);
      wfb[ct][kb] = load_wfrag(W1 + 64 * 64, 64, kb, ct, lane);
    }
  float b1v[4];
#pragma unroll
  for (int ct = 0; ct < 4; ++ct) b1v[ct] = b1[ct * 16 + (lane & 15)];
  __bf16* vb = xb[wid];
  int wgid = (blockIdx.x * blockDim.x + threadIdx.x) >> 6;
  int nw = (gridDim.x * blockDim.x) >> 6;
  for (int tile = wgid; tile < NN / 16; tile += nw) {
#pragma unroll
    for (int t = 0; t < 16; ++t)
      vb[t * 72 + lane] = (__bf16)x[(tile * 16 + t) * 64 + lane];
    const bf16x8 a0 = *(const bf16x8*)&vb[(lane & 15) * 72 + ((lane >> 4) << 3)];
    const bf16x8 a1 = *(const bf16x8*)&vb[(lane & 15) * 72 + 32 + ((lane >> 4) << 3)];
#pragma unroll
    for (int ct = 0; ct < 4; ++ct) {
      floatx4 aA = {0.f, 0.f, 0.f, 0.f}, aB = {0.f, 0.f, 0.f, 0.f};
      aA = MFMA16(a0, wfa[ct][0], aA);
      aA = MFMA16(a1, wfa[ct][1], aA);
      aB = MFMA16(a0, wfb[ct][0], aB);
      aB = MFMA16(a1, wfb[ct][1], aB);
#pragma unroll
      for (int r = 0; r < 4; ++r) {
        int row = ((lane >> 4) << 2) + r;
        int o = (tile * 16 + row) * 64 + ct * 16 + (lane & 15);
        Ab[o] = aA[r] + b1v[ct]; // fold b1 into A so h1 = A[i] + B[j]
        Bb[o] = aB[r];
      }
    }
  }
}

// KB: BN1 batch stats of h1 = A[i]+B[j] over all edges (CSR order for i-locality).
__global__ void k_edge_stats(const int* __restrict__ el, const int* __restrict__ ei,
                             const int* __restrict__ ej, const float* __restrict__ Ab,
                             const float* __restrict__ Bb, float* __restrict__ stats) {
  const int lane = threadIdx.x & 63;
  int wgid = (blockIdx.x * blockDim.x + threadIdx.x) >> 6;
  int nw = (gridDim.x * blockDim.x) >> 6;
  float ls = 0.f, lq = 0.f;
  for (int p = wgid; p < NE; p += nw) {
    int e = el[p];
    int i = ei[e], j = ej[e];
    float h = Ab[i * 64 + lane] + Bb[j * 64 + lane];
    ls += h;
    lq += h * h;
  }
  __shared__ float sred[128];
  if (threadIdx.x < 128) sred[threadIdx.x] = 0.f;
  __syncthreads();
  atomicAdd(&sred[lane], ls);
  atomicAdd(&sred[64 + lane], lq);
  __syncthreads();
  if (threadIdx.x < 128) atomicAdd(&stats[threadIdx.x], sred[threadIdx.x]);
}

// KC: v = relu(bn1(h1)); h2 = v@W2 + b2 (bf16 MFMA); accumulate BN2 stats;
// store h2 (bf16) at CSR position p so the scatter pass reads contiguously.
__global__ void __launch_bounds__(256) k_edge_mlp(
    const int* __restrict__ el, const int* __restrict__ ei, const int* __restrict__ ej,
    const float* __restrict__ Ab, const float* __restrict__ Bb,
    const float* __restrict__ g1, const float* __restrict__ be1,
    const float* __restrict__ W2, const float* __restrict__ b2,
    float* __restrict__ stats, __bf16* __restrict__ h2) {
  const int lane = threadIdx.x & 63;
  const int wid = threadIdx.x >> 6;
  __shared__ alignas(16) __bf16 vbuf[4][16 * 72];
  __shared__ float sred[128];
  float mu = stats[lane] * (1.f / NE);
  float var = stats[64 + lane] * (1.f / NE) - mu * mu;
  float s1 = g1[lane] * rsqrtf(var + BN_EPS);
  float t1 = be1[lane] - mu * s1;

  bf16x8 wf[4][2];
#pragma unroll
  for (int ct = 0; ct < 4; ++ct)
#pragma unroll
    for (int kb = 0; kb < 2; ++kb) wf[ct][kb] = load_wfrag(W2, 64, kb, ct, lane);
  float b2v[4];
#pragma unroll
  for (int ct = 0; ct < 4; ++ct) b2v[ct] = b2[ct * 16 + (lane & 15)];

  float sum2[4] = {0.f, 0.f, 0.f, 0.f}, ssq2[4] = {0.f, 0.f, 0.f, 0.f};
  __bf16* vb = vbuf[wid];
  int wgid = (blockIdx.x * blockDim.x + threadIdx.x) >> 6;
  int nw = (gridDim.x * blockDim.x) >> 6;
  for (int tile = wgid; tile < NE / 16; tile += nw) {
    int p0 = tile * 16;
    int e16 = el[p0 + (lane & 15)];
    int my_i = ei[e16];
    int my_j = ej[e16];
#pragma unroll
    for (int t = 0; t < 16; ++t) {
      int i = __shfl(my_i, t);
      int j = __shfl(my_j, t);
      float h = Ab[i * 64 + lane] + Bb[j * 64 + lane];
      vb[t * 72 + lane] = (__bf16)fmaxf(s1 * h + t1, 0.f);
    }
    const bf16x8 a0 = *(const bf16x8*)&vb[(lane & 15) * 72 + ((lane >> 4) << 3)];
    const bf16x8 a1 = *(const bf16x8*)&vb[(lane & 15) * 72 + 32 + ((lane >> 4) << 3)];
#pragma unroll
    for (int ct = 0; ct < 4; ++ct) {
      floatx4 acc = {0.f, 0.f, 0.f, 0.f};
      acc = MFMA16(a0, wf[ct][0], acc);
      acc = MFMA16(a1, wf[ct][1], acc);
#pragma unroll
      for (int r = 0; r < 4; ++r) {
        float hv = acc[r] + b2v[ct];
        sum2[ct] += hv;
        ssq2[ct] += hv * hv;
        int row = ((lane >> 4) << 2) + r;
        h2[(size_t)(p0 + row) * 64 + ct * 16 + (lane & 15)] = (__bf16)hv;
      }
    }
  }
  if (threadIdx.x < 128) sred[threadIdx.x] = 0.f;
  __syncthreads();
#pragma unroll
  for (int ct = 0; ct < 4; ++ct) {
    atomicAdd(&sred[ct * 16 + (lane & 15)], sum2[ct]);
    atomicAdd(&sred[64 + ct * 16 + (lane & 15)], ssq2[ct]);
  }
  __syncthreads();
  if (threadIdx.x < 128) atomicAdd(&stats[128 + threadIdx.x], sred[threadIdx.x]);
}

// KD: per-node reduction of relu(bn2(h2)) over contiguous CSR range, degree-normalized.
__global__ void k_scatter(const int* __restrict__ off, const float* __restrict__ dinv,
                          const float* __restrict__ g2, const float* __restrict__ be2,
                          const float* __restrict__ stats, const __bf16* __restrict__ h2,
                          float* __restrict__ outb) {
  const int lane = threadIdx.x & 63;
  int wgid = (blockIdx.x * blockDim.x + threadIdx.x) >> 6;
  int nw = (gridDim.x * blockDim.x) >> 6;
  float mu = stats[128 + lane] * (1.f / NE);
  float var = stats[192 + lane] * (1.f / NE) - mu * mu;
  float s2 = g2[lane] * rsqrtf(var + BN_EPS);
  float t2 = be2[lane] - mu * s2;
  for (int n = wgid; n < NN; n += nw) {
    int p0 = off[n], p1 = off[n + 1];
    float acc = 0.f;
    for (int p = p0; p < p1; ++p) {
      float h = (float)h2[(size_t)p * 64 + lane];
      acc += fmaxf(s2 * h + t2, 0.f);
    }
    outb[n * 64 + lane] = dinv[n] * acc;
  }
}

// KE: fused node update: upd = relu([x|fi|fo]@fcW + fcb)@fc2W + fc2b ; x += upd.
__global__ void __launch_bounds__(256) k_node_update(
    float* __restrict__ x, const float* __restrict__ fi, const float* __restrict__ fo,
    const float* __restrict__ fcW, const float* __restrict__ fcb,
    const float* __restrict__ fc2W, const float* __restrict__ fc2b) {
  const int lane = threadIdx.x & 63;
  const int wid = threadIdx.x >> 6;
  __shared__ alignas(16) __bf16 cat[16 * 200];
  __shared__ alignas(16) __bf16 v2[16 * 136];
  bf16x8 wf1[2][6];
#pragma unroll
  for (int c = 0; c < 2; ++c) {
    int ct = 2 * wid + c;
#pragma unroll
    for (int kb = 0; kb < 6; ++kb) wf1[c][kb] = load_wfrag(fcW, 128, kb, ct, lane);
  }
  bf16x8 wf2[4];
#pragma unroll
  for (int kb = 0; kb < 4; ++kb) wf2[kb] = load_wfrag(fc2W, 64, kb, wid, lane);
  float fcbv[2];
#pragma unroll
  for (int c = 0; c < 2; ++c) fcbv[c] = fcb[(2 * wid + c) * 16 + (lane & 15)];
  float fc2bv = fc2b[wid * 16 + (lane & 15)];

  for (int tile = blockIdx.x; tile < NN / 16; tile += gridDim.x) {
#pragma unroll
    for (int r = 0; r < 4; ++r) {
      int rr = wid * 4 + r;
      int n = tile * 16 + rr;
      cat[rr * 200 + lane] = (__bf16)x[n * 64 + lane];
      cat[rr * 200 + 64 + lane] = (__bf16)fi[n * 64 + lane];
      cat[rr * 200 + 128 + lane] = (__bf16)fo[n * 64 + lane];
    }
    __syncthreads();
    floatx4 acc0 = {0.f, 0.f, 0.f, 0.f}, acc1 = {0.f, 0.f, 0.f, 0.f};
#pragma unroll
    for (int kb = 0; kb < 6; ++kb) {
      bf16x8 af = *(const bf16x8*)&cat[(lane & 15) * 200 + kb * 32 + ((lane >> 4) << 3)];
      acc0 = MFMA16(af, wf1[0][kb], acc0);
      acc1 = MFMA16(af, wf1[1][kb], acc1);
    }
#pragma unroll
    for (int r = 0; r < 4; ++r) {
      int row = ((lane >> 4) << 2) + r;
      v2[row * 136 + (2 * wid) * 16 + (lane & 15)] = (__bf16)fmaxf(acc0[r] + fcbv[0], 0.f);
      v2[row * 136 + (2 * wid + 1) * 16 + (lane & 15)] = (__bf16)fmaxf(acc1[r] + fcbv[1], 0.f);
    }
    __syncthreads();
    floatx4 a2 = {0.f, 0.f, 0.f, 0.f};
#pragma unroll
    for (int kb = 0; kb < 4; ++kb) {
      bf16x8 af = *(const bf16x8*)&v2[(lane & 15) * 136 + kb * 32 + ((lane >> 4) << 3)];
      a2 = MFMA16(af, wf2[kb], a2);
    }
#pragma unroll
    for (int r = 0; r < 4; ++r) {
      int row = ((lane >> 4) << 2) + r;
      int n = tile * 16 + row;
      x[n * 64 + wid * 16 + (lane & 15)] += a2[r] + fc2bv;
    }
    __syncthreads();
  }
}

// KF: out = x@convW + convb (f32 for accuracy margin; weights in regs, shfl-broadcast x).
__global__ void __launch_bounds__(256) k_conv(const float* __restrict__ x,
                                              const float* __restrict__ convW,
                                              const float* __restrict__ convb,
                                              float* __restrict__ out) {
  const int lane = threadIdx.x & 63;
  int wgid = (blockIdx.x * blockDim.x + threadIdx.x) >> 6;
  int nw = (gridDim.x * blockDim.x) >> 6;
  int half = wgid & 1;
  int col = half * 64 + lane;
  float wreg[64];
#pragma unroll
  for (int k = 0; k < 64; ++k) wreg[k] = convW[k * 128 + col];
  float bv = convb[col];
  for (int n = (wgid >> 1); n < NN; n += (nw >> 1)) {
    float xv = x[n * 64 + lane];
    float acc = bv;
#pragma unroll
    for (int k = 0; k < 64; ++k) acc += __shfl(xv, k) * wreg[k];
    out[(size_t)n * 128 + col] = acc;
  }
}

extern "C" void kernel_launch(void* const* d_in, const int* in_sizes, int n_in,
                              void* d_out, int out_size, void* d_ws, size_t ws_size,
                              hipStream_t stream) {
  const int* nodes = (const int*)d_in[0];
  const int* edges = (const int*)d_in[1];
  const int* src = edges;      // edges[0]
  const int* dst = edges + NE; // edges[1]
  const float* emb = (const float*)d_in[2];
  const float* pW1 = (const float*)d_in[3];
  const float* pb1 = (const float*)d_in[4];
  const float* pg1 = (const float*)d_in[5];
  const float* pbe1 = (const float*)d_in[6];
  const float* pW2 = (const float*)d_in[7];
  const float* pb2 = (const float*)d_in[8];
  const float* pg2 = (const float*)d_in[9];
  const float* pbe2 = (const float*)d_in[10];
  const float* cW1 = (const float*)d_in[11];
  const float* cb1 = (const float*)d_in[12];
  const float* cg1 = (const float*)d_in[13];
  const float* cbe1 = (const float*)d_in[14];
  const float* cW2 = (const float*)d_in[15];
  const float* cb2 = (const float*)d_in[16];
  const float* cg2 = (const float*)d_in[17];
  const float* cbe2 = (const float*)d_in[18];
  const float* fcW = (const float*)d_in[19];
  const float* fcb = (const float*)d_in[20];
  const float* fc2W = (const float*)d_in[21];
  const float* fc2b = (const float*)d_in[22];
  const float* convW = (const float*)d_in[23];
  const float* convb = (const float*)d_in[24];
  float* out = (float*)d_out;

  char* w = (char*)d_ws;
  auto alloc = [&](size_t bytes) {
    char* p = w;
    w += (bytes + 255) & ~(size_t)255;
    return p;
  };
  float* x = (float*)alloc((size_t)NN * 64 * 4);
  float* Ab = (float*)alloc((size_t)NN * 64 * 4);
  float* Bb = (float*)alloc((size_t)NN * 64 * 4);
  float* fi = (float*)alloc((size_t)NN * 64 * 4);
  float* fo = (float*)alloc((size_t)NN * 64 * 4);
  __bf16* h2 = (__bf16*)alloc((size_t)NE * 64 * 2);
  int* el_d = (int*)alloc((size_t)NE * 4);
  int* el_s = (int*)alloc((size_t)NE * 4);
  int* off_d = (int*)alloc((size_t)(NN + 1) * 4);
  int* off_s = (int*)alloc((size_t)(NN + 1) * 4);
  int* cur_d = (int*)alloc((size_t)NN * 4);
  int* cur_s = (int*)alloc((size_t)NN * 4);
  int* cnt_d = (int*)alloc((size_t)NN * 4);
  int* cnt_s = (int*)alloc((size_t)NN * 4);
  float* dinv_d = (float*)alloc((size_t)NN * 4);
  float* dinv_s = (float*)alloc((size_t)NN * 4);
  float* stats = (float*)alloc(1024);
  int* btot = (int*)alloc(2 * SCAN_NB * 4);

  k_setup<<<1024, 256, 0, stream>>>(nodes, emb, x, cnt_d, cnt_s);
  k_hist<<<1024, 256, 0, stream>>>(src, dst, cnt_d, cnt_s);
  k_scan1<<<dim3(SCAN_NB, 2), SCAN_T, 0, stream>>>(cnt_d, cnt_s, off_d, off_s, btot);
  k_scan2<<<1, SCAN_T, 0, stream>>>(btot);
  k_scan3<<<dim3(SCAN_NB, 2), SCAN_T, 0, stream>>>(cnt_d, cnt_s, off_d, off_s, btot,
                                                   cur_d, cur_s, dinv_d, dinv_s);
  k_fill<<<1024, 256, 0, stream>>>(src, dst, cur_d, cur_s, el_d, el_s);

  for (int it = 0; it < 2; ++it) {
    // Parent aggregation: i = dst, j = src, scatter over dst-CSR -> fi
    k_node_xform<<<784, 256, 0, stream>>>(x, pW1, pb1, Ab, Bb, stats);
    k_edge_stats<<<2048, 256, 0, stream>>>(el_d, dst, src, Ab, Bb, stats);
    k_edge_mlp<<<4096, 256, 0, stream>>>(el_d, dst, src, Ab, Bb, pg1, pbe1, pW2, pb2, stats, h2);
    k_scatter<<<2048, 256, 0, stream>>>(off_d, dinv_d, pg2, pbe2, stats, h2, fi);
    // Child aggregation: i = src, j = dst, scatter over src-CSR -> fo
    k_node_xform<<<784, 256, 0, stream>>>(x, cW1, cb1, Ab, Bb, stats);
    k_edge_stats<<<2048, 256, 0, stream>>>(el_s, src, dst, Ab, Bb, stats);
    k_edge_mlp<<<4096, 256, 0, stream>>>(el_s, src, dst, Ab, Bb, cg1, cbe1, cW2, cb2, stats, h2);
    k_scatter<<<2048, 256, 0, stream>>>(off_s, dinv_s, cg2, cbe2, stats, h2, fo);
    // Node update
    k_node_update<<<3125, 256, 0, stream>>>(x, fi, fo, fcW, fcb, fc2W, fc2b);
  }
  k_conv<<<2048, 256, 0, stream>>>(x, convW, convb, out);
}

// Round 2
// 1323.052 us; speedup vs baseline: 1.4379x; 1.4379x over previous
//
#include <hip/hip_runtime.h>

#define NN 50000
#define NE 800000
#define BN_EPS 1e-5f
#define SCAN_T 256
#define SCAN_NB ((NN + SCAN_T - 1) / SCAN_T) // 196

// stats layout: per-aggregation block of 320 floats; parent at 0, child at 320
#define ST_SUM1 0
#define ST_SQ1 64
#define ST_CROSS 128
#define ST_SUM2 192
#define ST_SSQ2 256
#define ST_AGG 320

using bf16x8 = __attribute__((ext_vector_type(8))) __bf16;
using bf16x4 = __attribute__((ext_vector_type(4))) __bf16;
using bf16x2 = __attribute__((ext_vector_type(2))) __bf16;
using floatx4 = __attribute__((ext_vector_type(4))) float;

#define MFMA16(a, b, c) __builtin_amdgcn_mfma_f32_16x16x32_bf16(a, b, c, 0, 0, 0)

// W: row-major [K][ncols] f32. B-frag for 16x16x32: lane holds
// B[k = (lane>>4)*8 + j + kb*32][col = ct*16 + (lane&15)], j=0..7.
__device__ __forceinline__ bf16x8 load_wfrag(const float* W, int ncols, int kb, int ct, int lane) {
  int col = ct * 16 + (lane & 15);
  int k0 = kb * 32 + ((lane >> 4) << 3);
  bf16x8 f;
#pragma unroll
  for (int j = 0; j < 8; ++j) f[j] = (__bf16)W[(k0 + j) * ncols + col];
  return f;
}

// ---------------- setup ----------------
__global__ void k_setup(const int* __restrict__ nodes, const float* __restrict__ emb,
                        float* __restrict__ x, int* __restrict__ cnt_d, int* __restrict__ cnt_s) {
  int tid = blockIdx.x * blockDim.x + threadIdx.x;
  int stride = gridDim.x * blockDim.x;
  for (int idx = tid; idx < NN * 64; idx += stride)
    x[idx] = emb[nodes[idx >> 6] * 64 + (idx & 63)];
  for (int n = tid; n < NN; n += stride) { cnt_d[n] = 0; cnt_s[n] = 0; }
}

__global__ void k_hist(const int* __restrict__ src, const int* __restrict__ dst,
                       int* __restrict__ cnt_d, int* __restrict__ cnt_s) {
  int tid = blockIdx.x * blockDim.x + threadIdx.x;
  int stride = gridDim.x * blockDim.x;
  for (int e = tid; e < NE; e += stride) {
    atomicAdd(&cnt_d[dst[e]], 1);
    atomicAdd(&cnt_s[src[e]], 1);
  }
}

__global__ void k_scan1(const int* __restrict__ cnt_d, const int* __restrict__ cnt_s,
                        int* __restrict__ off_d, int* __restrict__ off_s, int* __restrict__ btot) {
  const int* cnt = blockIdx.y ? cnt_s : cnt_d;
  int* off = blockIdx.y ? off_s : off_d;
  __shared__ int sm[SCAN_T];
  int i = blockIdx.x * SCAN_T + threadIdx.x;
  int v = (i < NN) ? cnt[i] : 0;
  sm[threadIdx.x] = v;
  __syncthreads();
  for (int o = 1; o < SCAN_T; o <<= 1) {
    int u = (threadIdx.x >= o) ? sm[threadIdx.x - o] : 0;
    __syncthreads();
    sm[threadIdx.x] += u;
    __syncthreads();
  }
  if (i < NN) off[i] = sm[threadIdx.x]; // in-block inclusive (temp)
  if (threadIdx.x == SCAN_T - 1) btot[blockIdx.y * SCAN_NB + blockIdx.x] = sm[SCAN_T - 1];
}

__global__ void k_scan2(int* __restrict__ btot) {
  __shared__ int sm[SCAN_T];
  int t = threadIdx.x;
  for (int y = 0; y < 2; ++y) {
    int v = (t < SCAN_NB) ? btot[y * SCAN_NB + t] : 0;
    sm[t] = v;
    __syncthreads();
    for (int o = 1; o < SCAN_T; o <<= 1) {
      int u = (t >= o) ? sm[t - o] : 0;
      __syncthreads();
      sm[t] += u;
      __syncthreads();
    }
    if (t < SCAN_NB) btot[y * SCAN_NB + t] = sm[t] - v; // exclusive
    __syncthreads();
  }
}

__global__ void k_scan3(const int* __restrict__ cnt_d, const int* __restrict__ cnt_s,
                        int* __restrict__ off_d, int* __restrict__ off_s,
                        const int* __restrict__ btot, int* __restrict__ cur_d,
                        int* __restrict__ cur_s, float* __restrict__ dinv_d,
                        float* __restrict__ dinv_s) {
  const int* cnt = blockIdx.y ? cnt_s : cnt_d;
  int* off = blockIdx.y ? off_s : off_d;
  int* cur = blockIdx.y ? cur_s : cur_d;
  float* dinv = blockIdx.y ? dinv_s : dinv_d;
  int i = blockIdx.x * SCAN_T + threadIdx.x;
  if (i < NN) {
    int incl = off[i];
    int c = cnt[i];
    int o = incl - c + btot[blockIdx.y * SCAN_NB + blockIdx.x];
    off[i] = o;
    cur[i] = o;
    dinv[i] = c > 0 ? 1.0f / (float)c : 0.f;
  }
  if (i == NN - 1) off[NN] = NE;
}

// fill CSR-ordered (i,j) pairs so edge passes never gather indices
__global__ void k_fill(const int* __restrict__ src, const int* __restrict__ dst,
                       int* __restrict__ cur_d, int* __restrict__ cur_s,
                       int2* __restrict__ ij_d, int2* __restrict__ ij_s) {
  int tid = blockIdx.x * blockDim.x + threadIdx.x;
  int stride = gridDim.x * blockDim.x;
  for (int e = tid; e < NE; e += stride) {
    int s = src[e], d = dst[e];
    int p = atomicAdd(&cur_d[d], 1);
    ij_d[p] = make_int2(d, s);
    int q = atomicAdd(&cur_s[s], 1);
    ij_s[q] = make_int2(s, d);
  }
}

// ---------------- per-iteration kernels ----------------
// KA: A = x@W1[0:64] ; B = x@W1[64:128]  (biases cancel under BN -> dropped),
// bf16 outputs. do_zero: zero the stats buffer for this iteration.
__global__ void __launch_bounds__(256) k_node_xform(
    const float* __restrict__ x, const float* __restrict__ W1,
    __bf16* __restrict__ Ab, __bf16* __restrict__ Bb,
    float* __restrict__ stats, int do_zero) {
  const int lane = threadIdx.x & 63;
  const int wid = threadIdx.x >> 6;
  __shared__ alignas(16) __bf16 xb[4][16 * 72];
  if (do_zero && blockIdx.x == 0)
    for (int t = threadIdx.x; t < 2 * ST_AGG; t += blockDim.x) stats[t] = 0.f;
  bf16x8 wfa[4][2], wfb[4][2];
#pragma unroll
  for (int ct = 0; ct < 4; ++ct)
#pragma unroll
    for (int kb = 0; kb < 2; ++kb) {
      wfa[ct][kb] = load_wfrag(W1, 64, kb, ct, lane);
      wfb[ct][kb] = load_wfrag(W1 + 64 * 64, 64, kb, ct, lane);
    }
  __bf16* vb = xb[wid];
  int wgid = (blockIdx.x * blockDim.x + threadIdx.x) >> 6;
  int nw = (gridDim.x * blockDim.x) >> 6;
  for (int tile = wgid; tile < NN / 16; tile += nw) {
#pragma unroll
    for (int t = 0; t < 16; ++t)
      vb[t * 72 + lane] = (__bf16)x[(tile * 16 + t) * 64 + lane];
    const bf16x8 a0 = *(const bf16x8*)&vb[(lane & 15) * 72 + ((lane >> 4) << 3)];
    const bf16x8 a1 = *(const bf16x8*)&vb[(lane & 15) * 72 + 32 + ((lane >> 4) << 3)];
#pragma unroll
    for (int ct = 0; ct < 4; ++ct) {
      floatx4 aA = {0.f, 0.f, 0.f, 0.f}, aB = {0.f, 0.f, 0.f, 0.f};
      aA = MFMA16(a0, wfa[ct][0], aA);
      aA = MFMA16(a1, wfa[ct][1], aA);
      aB = MFMA16(a0, wfb[ct][0], aB);
      aB = MFMA16(a1, wfb[ct][1], aB);
#pragma unroll
      for (int r = 0; r < 4; ++r) {
        int row = ((lane >> 4) << 2) + r;
        int o = (tile * 16 + row) * 64 + ct * 16 + (lane & 15);
        Ab[o] = (__bf16)aA[r];
        Bb[o] = (__bf16)aB[r];
      }
    }
  }
}

// KB: degree-weighted node sums for BN1 of BOTH aggregations (O(N), replaces
// the mean/sq part of the old edge-stats pass).
// parent h1 = Ap[dst]+Bp[src]; child h1 = Ac[src]+Bc[dst].
__global__ void __launch_bounds__(256) k_node_stats(
    const __bf16* __restrict__ Ap, const __bf16* __restrict__ Bp,
    const __bf16* __restrict__ Ac, const __bf16* __restrict__ Bc,
    const int* __restrict__ cnt_d, const int* __restrict__ cnt_s,
    float* __restrict__ stats) {
  const int lane = threadIdx.x & 63;
  const int g = lane >> 4, q = lane & 15;
  __shared__ float sacc[256];
  for (int t = threadIdx.x; t < 256; t += blockDim.x) sacc[t] = 0.f;
  __syncthreads();
  float sp[4] = {0, 0, 0, 0}, qp[4] = {0, 0, 0, 0};
  float sc[4] = {0, 0, 0, 0}, qc[4] = {0, 0, 0, 0};
  int wgid = (blockIdx.x * blockDim.x + threadIdx.x) >> 6;
  int nw = (gridDim.x * blockDim.x) >> 6;
  for (int ch = wgid; ch < NN / 4; ch += nw) {
    int n = ch * 4 + g;
    float wd = (float)cnt_d[n];
    float ws = (float)cnt_s[n];
    bf16x4 ap = *(const bf16x4*)(Ap + n * 64 + 4 * q);
    bf16x4 bp = *(const bf16x4*)(Bp + n * 64 + 4 * q);
    bf16x4 ac = *(const bf16x4*)(Ac + n * 64 + 4 * q);
    bf16x4 bc = *(const bf16x4*)(Bc + n * 64 + 4 * q);
#pragma unroll
    for (int k = 0; k < 4; ++k) {
      float a = (float)ap[k], b = (float)bp[k], c = (float)ac[k], d = (float)bc[k];
      sp[k] += wd * a + ws * b;
      qp[k] += wd * a * a + ws * b * b;
      sc[k] += ws * c + wd * d;
      qc[k] += ws * c * c + wd * d * d;
    }
  }
#pragma unroll
  for (int k = 0; k < 4; ++k) {
    sp[k] += __shfl_xor(sp[k], 16); sp[k] += __shfl_xor(sp[k], 32);
    qp[k] += __shfl_xor(qp[k], 16); qp[k] += __shfl_xor(qp[k], 32);
    sc[k] += __shfl_xor(sc[k], 16); sc[k] += __shfl_xor(sc[k], 32);
    qc[k] += __shfl_xor(qc[k], 16); qc[k] += __shfl_xor(qc[k], 32);
  }
  if (lane < 16) {
#pragma unroll
    for (int k = 0; k < 4; ++k) {
      atomicAdd(&sacc[4 * q + k], sp[k]);
      atomicAdd(&sacc[64 + 4 * q + k], qp[k]);
      atomicAdd(&sacc[128 + 4 * q + k], sc[k]);
      atomicAdd(&sacc[192 + 4 * q + k], qc[k]);
    }
  }
  __syncthreads();
  for (int t = threadIdx.x; t < 256; t += blockDim.x) {
    int dstoff = (t < 128) ? t : ST_AGG + (t - 128); // SUM1/SQ1 contiguous per agg
    atomicAdd(&stats[dstoff], sacc[t]);
  }
}

// KC: cross terms sum_e Ap[dst]*Bp[src] and sum_e Ac[src]*Bc[dst], per column.
// Single fused pass over edges in plain order (contiguous index reads).
__global__ void __launch_bounds__(256) k_cross(
    const int* __restrict__ src, const int* __restrict__ dst,
    const __bf16* __restrict__ Ap, const __bf16* __restrict__ Bp,
    const __bf16* __restrict__ Ac, const __bf16* __restrict__ Bc,
    float* __restrict__ stats) {
  const int lane = threadIdx.x & 63;
  const int g = lane >> 4, q = lane & 15;
  __shared__ float sacc[128];
  for (int t = threadIdx.x; t < 128; t += blockDim.x) sacc[t] = 0.f;
  __syncthreads();
  float cp[4] = {0, 0, 0, 0}, cc[4] = {0, 0, 0, 0};
  int wgid = (blockIdx.x * blockDim.x + threadIdx.x) >> 6;
  int nw = (gridDim.x * blockDim.x) >> 6;
  for (int ch = wgid; ch < NE / 64; ch += nw) {
    int e0 = ch * 64;
    int s64 = src[e0 + lane];
    int d64 = dst[e0 + lane];
#pragma unroll 4
    for (int t = 0; t < 16; ++t) {
      int u = t * 4 + g;
      int s = __shfl(s64, u);
      int d = __shfl(d64, u);
      bf16x4 ap = *(const bf16x4*)(Ap + d * 64 + 4 * q);
      bf16x4 bp = *(const bf16x4*)(Bp + s * 64 + 4 * q);
      bf16x4 ac = *(const bf16x4*)(Ac + s * 64 + 4 * q);
      bf16x4 bc = *(const bf16x4*)(Bc + d * 64 + 4 * q);
#pragma unroll
      for (int k = 0; k < 4; ++k) {
        cp[k] += (float)ap[k] * (float)bp[k];
        cc[k] += (float)ac[k] * (float)bc[k];
      }
    }
  }
#pragma unroll
  for (int k = 0; k < 4; ++k) {
    cp[k] += __shfl_xor(cp[k], 16); cp[k] += __shfl_xor(cp[k], 32);
    cc[k] += __shfl_xor(cc[k], 16); cc[k] += __shfl_xor(cc[k], 32);
  }
  if (lane < 16) {
#pragma unroll
    for (int k = 0; k < 4; ++k) {
      atomicAdd(&sacc[4 * q + k], cp[k]);
      atomicAdd(&sacc[64 + 4 * q + k], cc[k]);
    }
  }
  __syncthreads();
  for (int t = threadIdx.x; t < 128; t += blockDim.x) {
    int dstoff = (t < 64) ? (ST_CROSS + t) : (ST_AGG + ST_CROSS + (t - 64));
    atomicAdd(&stats[dstoff], sacc[t]);
  }
}

// KD: v = relu(bn1(A[i]+B[j])); h2 = v@W2 (b2 cancels in BN2); accumulate BN2
// stats; store h2 bf16 at CSR position p. 4 edges per gather instruction.
__global__ void __launch_bounds__(256) k_edge_mlp(
    const int2* __restrict__ ij, const __bf16* __restrict__ A_,
    const __bf16* __restrict__ B_, const float* __restrict__ g1,
    const float* __restrict__ be1, const float* __restrict__ W2,
    float* __restrict__ stats, int sbase, __bf16* __restrict__ h2) {
  const int lane = threadIdx.x & 63;
  const int wid = threadIdx.x >> 6;
  const int g = lane >> 4, q = lane & 15;
  __shared__ alignas(16) __bf16 vbuf[4][16 * 72];
  __shared__ float sred[128];
  float s1v[4], t1v[4];
#pragma unroll
  for (int k = 0; k < 4; ++k) {
    int c = 4 * q + k;
    float mu = stats[sbase + ST_SUM1 + c] * (1.f / NE);
    float var = (stats[sbase + ST_SQ1 + c] + 2.f * stats[sbase + ST_CROSS + c]) * (1.f / NE) - mu * mu;
    float s1 = g1[c] * rsqrtf(var + BN_EPS);
    s1v[k] = s1;
    t1v[k] = be1[c] - mu * s1;
  }
  bf16x8 wf[4][2];
#pragma unroll
  for (int ct = 0; ct < 4; ++ct)
#pragma unroll
    for (int kb = 0; kb < 2; ++kb) wf[ct][kb] = load_wfrag(W2, 64, kb, ct, lane);

  float sum2[4] = {0, 0, 0, 0}, ssq2[4] = {0, 0, 0, 0};
  __bf16* vb = vbuf[wid];
  int wgid = (blockIdx.x * blockDim.x + threadIdx.x) >> 6;
  int nw = (gridDim.x * blockDim.x) >> 6;
  for (int tile = wgid; tile < NE / 16; tile += nw) {
    int p0 = tile * 16;
    int2 ij16 = ij[p0 + q];
#pragma unroll
    for (int t = 0; t < 4; ++t) {
      int u = t * 4 + g;
      int i = __shfl(ij16.x, u);
      int j = __shfl(ij16.y, u);
      bf16x4 a4 = *(const bf16x4*)(A_ + i * 64 + 4 * q);
      bf16x4 b4 = *(const bf16x4*)(B_ + j * 64 + 4 * q);
      bf16x4 v4;
#pragma unroll
      for (int k = 0; k < 4; ++k) {
        float h = (float)a4[k] + (float)b4[k];
        v4[k] = (__bf16)fmaxf(s1v[k] * h + t1v[k], 0.f);
      }
      *(bf16x4*)&vb[u * 72 + 4 * q] = v4;
    }
    const bf16x8 a0 = *(const bf16x8*)&vb[q * 72 + g * 8];
    const bf16x8 a1 = *(const bf16x8*)&vb[q * 72 + 32 + g * 8];
#pragma unroll
    for (int ct = 0; ct < 4; ++ct) {
      floatx4 acc = {0.f, 0.f, 0.f, 0.f};
      acc = MFMA16(a0, wf[ct][0], acc);
      acc = MFMA16(a1, wf[ct][1], acc);
#pragma unroll
      for (int r = 0; r < 4; ++r) {
        float hv = acc[r];
        sum2[ct] += hv;
        ssq2[ct] += hv * hv;
        int row = g * 4 + r;
        h2[(size_t)(p0 + row) * 64 + ct * 16 + q] = (__bf16)hv;
      }
    }
  }
  if (threadIdx.x < 128) sred[threadIdx.x] = 0.f;
  __syncthreads();
#pragma unroll
  for (int ct = 0; ct < 4; ++ct) {
    atomicAdd(&sred[ct * 16 + q], sum2[ct]);
    atomicAdd(&sred[64 + ct * 16 + q], ssq2[ct]);
  }
  __syncthreads();
  if (threadIdx.x < 128) atomicAdd(&stats[sbase + ST_SUM2 + threadIdx.x], sred[threadIdx.x]);
}

// KE: per-node reduction of relu(bn2(h2)) over contiguous CSR range.
// Half-wave per h2 row (bf16x2/lane), float2 coalesced output.
__global__ void k_scatter(const int* __restrict__ off, const float* __restrict__ dinv,
                          const float* __restrict__ g2, const float* __restrict__ be2,
                          const float* __restrict__ stats, int sbase,
                          const __bf16* __restrict__ h2, float* __restrict__ outb) {
  const int lane = threadIdx.x & 63;
  const int m = lane & 31, half = lane >> 5;
  float s2x, s2y, t2x, t2y;
  {
    int c0 = 2 * m, c1 = 2 * m + 1;
    float mu0 = stats[sbase + ST_SUM2 + c0] * (1.f / NE);
    float mu1 = stats[sbase + ST_SUM2 + c1] * (1.f / NE);
    float v0 = stats[sbase + ST_SSQ2 + c0] * (1.f / NE) - mu0 * mu0;
    float v1 = stats[sbase + ST_SSQ2 + c1] * (1.f / NE) - mu1 * mu1;
    s2x = g2[c0] * rsqrtf(v0 + BN_EPS);
    s2y = g2[c1] * rsqrtf(v1 + BN_EPS);
    t2x = be2[c0] - mu0 * s2x;
    t2y = be2[c1] - mu1 * s2y;
  }
  int wgid = (blockIdx.x * blockDim.x + threadIdx.x) >> 6;
  int nw = (gridDim.x * blockDim.x) >> 6;
  for (int n = wgid; n < NN; n += nw) {
    int p0 = off[n], p1 = off[n + 1];
    float ax = 0.f, ay = 0.f;
    for (int p = p0 + half; p < p1; p += 2) {
      bf16x2 h = *(const bf16x2*)(h2 + (size_t)p * 64 + 2 * m);
      ax += fmaxf(s2x * (float)h[0] + t2x, 0.f);
      ay += fmaxf(s2y * (float)h[1] + t2y, 0.f);
    }
    ax += __shfl_xor(ax, 32);
    ay += __shfl_xor(ay, 32);
    if (half == 0) {
      float dv = dinv[n];
      *(float2*)&outb[n * 64 + 2 * m] = make_float2(dv * ax, dv * ay);
    }
  }
}

// KF: fused node update: upd = relu([x|fi|fo]@fcW + fcb)@fc2W + fc2b ; x += upd.
__global__ void __launch_bounds__(256) k_node_update(
    float* __restrict__ x, const float* __restrict__ fi, const float* __restrict__ fo,
    const float* __restrict__ fcW, const float* __restrict__ fcb,
    const float* __restrict__ fc2W, const float* __restrict__ fc2b) {
  const int lane = threadIdx.x & 63;
  const int wid = threadIdx.x >> 6;
  __shared__ alignas(16) __bf16 cat[16 * 200];
  __shared__ alignas(16) __bf16 v2[16 * 136];
  bf16x8 wf1[2][6];
#pragma unroll
  for (int c = 0; c < 2; ++c) {
    int ct = 2 * wid + c;
#pragma unroll
    for (int kb = 0; kb < 6; ++kb) wf1[c][kb] = load_wfrag(fcW, 128, kb, ct, lane);
  }
  bf16x8 wf2[4];
#pragma unroll
  for (int kb = 0; kb < 4; ++kb) wf2[kb] = load_wfrag(fc2W, 64, kb, wid, lane);
  float fcbv[2];
#pragma unroll
  for (int c = 0; c < 2; ++c) fcbv[c] = fcb[(2 * wid + c) * 16 + (lane & 15)];
  float fc2bv = fc2b[wid * 16 + (lane & 15)];

  for (int tile = blockIdx.x; tile < NN / 16; tile += gridDim.x) {
#pragma unroll
    for (int r = 0; r < 4; ++r) {
      int rr = wid * 4 + r;
      int n = tile * 16 + rr;
      cat[rr * 200 + lane] = (__bf16)x[n * 64 + lane];
      cat[rr * 200 + 64 + lane] = (__bf16)fi[n * 64 + lane];
      cat[rr * 200 + 128 + lane] = (__bf16)fo[n * 64 + lane];
    }
    __syncthreads();
    floatx4 acc0 = {0.f, 0.f, 0.f, 0.f}, acc1 = {0.f, 0.f, 0.f, 0.f};
#pragma unroll
    for (int kb = 0; kb < 6; ++kb) {
      bf16x8 af = *(const bf16x8*)&cat[(lane & 15) * 200 + kb * 32 + ((lane >> 4) << 3)];
      acc0 = MFMA16(af, wf1[0][kb], acc0);
      acc1 = MFMA16(af, wf1[1][kb], acc1);
    }
#pragma unroll
    for (int r = 0; r < 4; ++r) {
      int row = ((lane >> 4) << 2) + r;
      v2[row * 136 + (2 * wid) * 16 + (lane & 15)] = (__bf16)fmaxf(acc0[r] + fcbv[0], 0.f);
      v2[row * 136 + (2 * wid + 1) * 16 + (lane & 15)] = (__bf16)fmaxf(acc1[r] + fcbv[1], 0.f);
    }
    __syncthreads();
    floatx4 a2 = {0.f, 0.f, 0.f, 0.f};
#pragma unroll
    for (int kb = 0; kb < 4; ++kb) {
      bf16x8 af = *(const bf16x8*)&v2[(lane & 15) * 136 + kb * 32 + ((lane >> 4) << 3)];
      a2 = MFMA16(af, wf2[kb], a2);
    }
#pragma unroll
    for (int r = 0; r < 4; ++r) {
      int row = ((lane >> 4) << 2) + r;
      int n = tile * 16 + row;
      x[n * 64 + wid * 16 + (lane & 15)] += a2[r] + fc2bv;
    }
    __syncthreads();
  }
}

// KG: out = x@convW + convb (f32 for accuracy margin).
__global__ void __launch_bounds__(256) k_conv(const float* __restrict__ x,
                                              const float* __restrict__ convW,
                                              const float* __restrict__ convb,
                                              float* __restrict__ out) {
  const int lane = threadIdx.x & 63;
  int wgid = (blockIdx.x * blockDim.x + threadIdx.x) >> 6;
  int nw = (gridDim.x * blockDim.x) >> 6;
  int half = wgid & 1;
  int col = half * 64 + lane;
  float wreg[64];
#pragma unroll
  for (int k = 0; k < 64; ++k) wreg[k] = convW[k * 128 + col];
  float bv = convb[col];
  for (int n = (wgid >> 1); n < NN; n += (nw >> 1)) {
    float xv = x[n * 64 + lane];
    float acc = bv;
#pragma unroll
    for (int k = 0; k < 64; ++k) acc += __shfl(xv, k) * wreg[k];
    out[(size_t)n * 128 + col] = acc;
  }
}

extern "C" void kernel_launch(void* const* d_in, const int* in_sizes, int n_in,
                              void* d_out, int out_size, void* d_ws, size_t ws_size,
                              hipStream_t stream) {
  const int* nodes = (const int*)d_in[0];
  const int* edges = (const int*)d_in[1];
  const int* src = edges;      // edges[0]
  const int* dst = edges + NE; // edges[1]
  const float* emb = (const float*)d_in[2];
  const float* pW1 = (const float*)d_in[3];
  const float* pg1 = (const float*)d_in[5];
  const float* pbe1 = (const float*)d_in[6];
  const float* pW2 = (const float*)d_in[7];
  const float* pg2 = (const float*)d_in[9];
  const float* pbe2 = (const float*)d_in[10];
  const float* cW1 = (const float*)d_in[11];
  const float* cg1 = (const float*)d_in[13];
  const float* cbe1 = (const float*)d_in[14];
  const float* cW2 = (const float*)d_in[15];
  const float* cg2 = (const float*)d_in[17];
  const float* cbe2 = (const float*)d_in[18];
  const float* fcW = (const float*)d_in[19];
  const float* fcb = (const float*)d_in[20];
  const float* fc2W = (const float*)d_in[21];
  const float* fc2b = (const float*)d_in[22];
  const float* convW = (const float*)d_in[23];
  const float* convb = (const float*)d_in[24];
  float* out = (float*)d_out;

  char* w = (char*)d_ws;
  auto alloc = [&](size_t bytes) {
    char* p = w;
    w += (bytes + 255) & ~(size_t)255;
    return p;
  };
  float* x = (float*)alloc((size_t)NN * 64 * 4);
  __bf16* Ap = (__bf16*)alloc((size_t)NN * 64 * 2);
  __bf16* Bp = (__bf16*)alloc((size_t)NN * 64 * 2);
  __bf16* Ac = (__bf16*)alloc((size_t)NN * 64 * 2);
  __bf16* Bc = (__bf16*)alloc((size_t)NN * 64 * 2);
  float* fi = (float*)alloc((size_t)NN * 64 * 4);
  float* fo = (float*)alloc((size_t)NN * 64 * 4);
  __bf16* h2 = (__bf16*)alloc((size_t)NE * 64 * 2);
  int2* ij_d = (int2*)alloc((size_t)NE * 8);
  int2* ij_s = (int2*)alloc((size_t)NE * 8);
  int* off_d = (int*)alloc((size_t)(NN + 1) * 4);
  int* off_s = (int*)alloc((size_t)(NN + 1) * 4);
  int* cur_d = (int*)alloc((size_t)NN * 4);
  int* cur_s = (int*)alloc((size_t)NN * 4);
  int* cnt_d = (int*)alloc((size_t)NN * 4);
  int* cnt_s = (int*)alloc((size_t)NN * 4);
  float* dinv_d = (float*)alloc((size_t)NN * 4);
  float* dinv_s = (float*)alloc((size_t)NN * 4);
  float* stats = (float*)alloc(2 * ST_AGG * 4);
  int* btot = (int*)alloc(2 * SCAN_NB * 4);

  k_setup<<<1024, 256, 0, stream>>>(nodes, emb, x, cnt_d, cnt_s);
  k_hist<<<1024, 256, 0, stream>>>(src, dst, cnt_d, cnt_s);
  k_scan1<<<dim3(SCAN_NB, 2), SCAN_T, 0, stream>>>(cnt_d, cnt_s, off_d, off_s, btot);
  k_scan2<<<1, SCAN_T, 0, stream>>>(btot);
  k_scan3<<<dim3(SCAN_NB, 2), SCAN_T, 0, stream>>>(cnt_d, cnt_s, off_d, off_s, btot,
                                                   cur_d, cur_s, dinv_d, dinv_s);
  k_fill<<<1024, 256, 0, stream>>>(src, dst, cur_d, cur_s, ij_d, ij_s);

  for (int it = 0; it < 2; ++it) {
    k_node_xform<<<784, 256, 0, stream>>>(x, pW1, Ap, Bp, stats, 1);
    k_node_xform<<<784, 256, 0, stream>>>(x, cW1, Ac, Bc, stats, 0);
    k_node_stats<<<256, 256, 0, stream>>>(Ap, Bp, Ac, Bc, cnt_d, cnt_s, stats);
    k_cross<<<1024, 256, 0, stream>>>(src, dst, Ap, Bp, Ac, Bc, stats);
    // Parent: i = dst, j = src, dst-CSR -> fi
    k_edge_mlp<<<4096, 256, 0, stream>>>(ij_d, Ap, Bp, pg1, pbe1, pW2, stats, 0, h2);
    k_scatter<<<2048, 256, 0, stream>>>(off_d, dinv_d, pg2, pbe2, stats, 0, h2, fi);
    // Child: i = src, j = dst, src-CSR -> fo
    k_edge_mlp<<<4096, 256, 0, stream>>>(ij_s, Ac, Bc, cg1, cbe1, cW2, stats, ST_AGG, h2);
    k_scatter<<<2048, 256, 0, stream>>>(off_s, dinv_s, cg2, cbe2, stats, ST_AGG, h2, fo);
    // Node update
    k_node_update<<<3125, 256, 0, stream>>>(x, fi, fo, fcW, fcb, fc2W, fc2b);
  }
  k_conv<<<2048, 256, 0, stream>>>(x, convW, convb, out);
}

// Round 3
// 1092.717 us; speedup vs baseline: 1.7410x; 1.2108x over previous
//
#include <hip/hip_runtime.h>

#define NN 50000
#define NE 800000
#define BN_EPS 1e-5f
#define SCAN_T 256
#define SCAN_NB ((NN + SCAN_T - 1) / SCAN_T) // 196

// stats layout: per-aggregation block of 320 floats; parent at 0, child at 320
#define ST_SUM1 0
#define ST_SQ1 64
#define ST_CROSS 128
#define ST_SUM2 192
#define ST_SSQ2 256
#define ST_AGG 320

using bf16x8 = __attribute__((ext_vector_type(8))) __bf16;
using bf16x4 = __attribute__((ext_vector_type(4))) __bf16;
using floatx4 = __attribute__((ext_vector_type(4))) float;

#define MFMA16(a, b, c) __builtin_amdgcn_mfma_f32_16x16x32_bf16(a, b, c, 0, 0, 0)

// W: row-major [K][ncols] f32. B-frag for 16x16x32: lane holds
// B[k = (lane>>4)*8 + j + kb*32][col = ct*16 + (lane&15)], j=0..7.
__device__ __forceinline__ bf16x8 load_wfrag(const float* W, int ncols, int kb, int ct, int lane) {
  int col = ct * 16 + (lane & 15);
  int k0 = kb * 32 + ((lane >> 4) << 3);
  bf16x8 f;
#pragma unroll
  for (int j = 0; j < 8; ++j) f[j] = (__bf16)W[(k0 + j) * ncols + col];
  return f;
}

// ---------------- setup ----------------
__global__ void k_setup(const int* __restrict__ nodes, const float* __restrict__ emb,
                        float* __restrict__ x, int* __restrict__ cnt_d, int* __restrict__ cnt_s) {
  int tid = blockIdx.x * blockDim.x + threadIdx.x;
  int stride = gridDim.x * blockDim.x;
  for (int idx = tid; idx < NN * 64; idx += stride)
    x[idx] = emb[nodes[idx >> 6] * 64 + (idx & 63)];
  for (int n = tid; n < NN; n += stride) { cnt_d[n] = 0; cnt_s[n] = 0; }
}

__global__ void k_hist(const int* __restrict__ src, const int* __restrict__ dst,
                       int* __restrict__ cnt_d, int* __restrict__ cnt_s) {
  int tid = blockIdx.x * blockDim.x + threadIdx.x;
  int stride = gridDim.x * blockDim.x;
  for (int e = tid; e < NE; e += stride) {
    atomicAdd(&cnt_d[dst[e]], 1);
    atomicAdd(&cnt_s[src[e]], 1);
  }
}

__global__ void k_scan1(const int* __restrict__ cnt_d, const int* __restrict__ cnt_s,
                        int* __restrict__ off_d, int* __restrict__ off_s, int* __restrict__ btot) {
  const int* cnt = blockIdx.y ? cnt_s : cnt_d;
  int* off = blockIdx.y ? off_s : off_d;
  __shared__ int sm[SCAN_T];
  int i = blockIdx.x * SCAN_T + threadIdx.x;
  int v = (i < NN) ? cnt[i] : 0;
  sm[threadIdx.x] = v;
  __syncthreads();
  for (int o = 1; o < SCAN_T; o <<= 1) {
    int u = (threadIdx.x >= o) ? sm[threadIdx.x - o] : 0;
    __syncthreads();
    sm[threadIdx.x] += u;
    __syncthreads();
  }
  if (i < NN) off[i] = sm[threadIdx.x]; // in-block inclusive (temp)
  if (threadIdx.x == SCAN_T - 1) btot[blockIdx.y * SCAN_NB + blockIdx.x] = sm[SCAN_T - 1];
}

__global__ void k_scan2(int* __restrict__ btot) {
  __shared__ int sm[SCAN_T];
  int t = threadIdx.x;
  for (int y = 0; y < 2; ++y) {
    int v = (t < SCAN_NB) ? btot[y * SCAN_NB + t] : 0;
    sm[t] = v;
    __syncthreads();
    for (int o = 1; o < SCAN_T; o <<= 1) {
      int u = (t >= o) ? sm[t - o] : 0;
      __syncthreads();
      sm[t] += u;
      __syncthreads();
    }
    if (t < SCAN_NB) btot[y * SCAN_NB + t] = sm[t] - v; // exclusive
    __syncthreads();
  }
}

__global__ void k_scan3(const int* __restrict__ cnt_d, const int* __restrict__ cnt_s,
                        int* __restrict__ off_d, int* __restrict__ off_s,
                        const int* __restrict__ btot, int* __restrict__ cur_d,
                        int* __restrict__ cur_s, float* __restrict__ dinv_d,
                        float* __restrict__ dinv_s) {
  const int* cnt = blockIdx.y ? cnt_s : cnt_d;
  int* off = blockIdx.y ? off_s : off_d;
  int* cur = blockIdx.y ? cur_s : cur_d;
  float* dinv = blockIdx.y ? dinv_s : dinv_d;
  int i = blockIdx.x * SCAN_T + threadIdx.x;
  if (i < NN) {
    int incl = off[i];
    int c = cnt[i];
    int o = incl - c + btot[blockIdx.y * SCAN_NB + blockIdx.x];
    off[i] = o;
    cur[i] = o;
    dinv[i] = c > 0 ? 1.0f / (float)c : 0.f;
  }
  if (i == NN - 1) off[NN] = NE;
}

// fill CSR-ordered j-lists (i is implicit = CSR row)
__global__ void k_fill(const int* __restrict__ src, const int* __restrict__ dst,
                       int* __restrict__ cur_d, int* __restrict__ cur_s,
                       int* __restrict__ jl_d, int* __restrict__ jl_s) {
  int tid = blockIdx.x * blockDim.x + threadIdx.x;
  int stride = gridDim.x * blockDim.x;
  for (int e = tid; e < NE; e += stride) {
    int s = src[e], d = dst[e];
    int p = atomicAdd(&cur_d[d], 1);
    jl_d[p] = s;
    int q2 = atomicAdd(&cur_s[s], 1);
    jl_s[q2] = d;
  }
}

// ---------------- per-iteration kernels ----------------
// KA: A = x@W1[0:64] ; B = x@W1[64:128]  (biases cancel under BN -> dropped),
// bf16 outputs. do_zero: zero the stats buffer for this iteration.
__global__ void __launch_bounds__(256) k_node_xform(
    const float* __restrict__ x, const float* __restrict__ W1,
    __bf16* __restrict__ Ab, __bf16* __restrict__ Bb,
    float* __restrict__ stats, int do_zero) {
  const int lane = threadIdx.x & 63;
  const int wid = threadIdx.x >> 6;
  __shared__ alignas(16) __bf16 xb[4][16 * 72];
  if (do_zero && blockIdx.x == 0)
    for (int t = threadIdx.x; t < 2 * ST_AGG; t += blockDim.x) stats[t] = 0.f;
  bf16x8 wfa[4][2], wfb[4][2];
#pragma unroll
  for (int ct = 0; ct < 4; ++ct)
#pragma unroll
    for (int kb = 0; kb < 2; ++kb) {
      wfa[ct][kb] = load_wfrag(W1, 64, kb, ct, lane);
      wfb[ct][kb] = load_wfrag(W1 + 64 * 64, 64, kb, ct, lane);
    }
  __bf16* vb = xb[wid];
  int wgid = (blockIdx.x * blockDim.x + threadIdx.x) >> 6;
  int nw = (gridDim.x * blockDim.x) >> 6;
  for (int tile = wgid; tile < NN / 16; tile += nw) {
#pragma unroll
    for (int t = 0; t < 16; ++t)
      vb[t * 72 + lane] = (__bf16)x[(tile * 16 + t) * 64 + lane];
    const bf16x8 a0 = *(const bf16x8*)&vb[(lane & 15) * 72 + ((lane >> 4) << 3)];
    const bf16x8 a1 = *(const bf16x8*)&vb[(lane & 15) * 72 + 32 + ((lane >> 4) << 3)];
#pragma unroll
    for (int ct = 0; ct < 4; ++ct) {
      floatx4 aA = {0.f, 0.f, 0.f, 0.f}, aB = {0.f, 0.f, 0.f, 0.f};
      aA = MFMA16(a0, wfa[ct][0], aA);
      aA = MFMA16(a1, wfa[ct][1], aA);
      aB = MFMA16(a0, wfb[ct][0], aB);
      aB = MFMA16(a1, wfb[ct][1], aB);
#pragma unroll
      for (int r = 0; r < 4; ++r) {
        int row = ((lane >> 4) << 2) + r;
        int o = (tile * 16 + row) * 64 + ct * 16 + (lane & 15);
        Ab[o] = (__bf16)aA[r];
        Bb[o] = (__bf16)aB[r];
      }
    }
  }
}

// KB: degree-weighted node sums for BN1 of BOTH aggregations (O(N)).
__global__ void __launch_bounds__(256) k_node_stats(
    const __bf16* __restrict__ Ap, const __bf16* __restrict__ Bp,
    const __bf16* __restrict__ Ac, const __bf16* __restrict__ Bc,
    const int* __restrict__ cnt_d, const int* __restrict__ cnt_s,
    float* __restrict__ stats) {
  const int lane = threadIdx.x & 63;
  const int g = lane >> 4, q = lane & 15;
  __shared__ float sacc[256];
  for (int t = threadIdx.x; t < 256; t += blockDim.x) sacc[t] = 0.f;
  __syncthreads();
  float sp[4] = {0, 0, 0, 0}, qp[4] = {0, 0, 0, 0};
  float sc[4] = {0, 0, 0, 0}, qc[4] = {0, 0, 0, 0};
  int wgid = (blockIdx.x * blockDim.x + threadIdx.x) >> 6;
  int nw = (gridDim.x * blockDim.x) >> 6;
  for (int ch = wgid; ch < NN / 4; ch += nw) {
    int n = ch * 4 + g;
    float wd = (float)cnt_d[n];
    float ws = (float)cnt_s[n];
    bf16x4 ap = *(const bf16x4*)(Ap + n * 64 + 4 * q);
    bf16x4 bp = *(const bf16x4*)(Bp + n * 64 + 4 * q);
    bf16x4 ac = *(const bf16x4*)(Ac + n * 64 + 4 * q);
    bf16x4 bc = *(const bf16x4*)(Bc + n * 64 + 4 * q);
#pragma unroll
    for (int k = 0; k < 4; ++k) {
      float a = (float)ap[k], b = (float)bp[k], c = (float)ac[k], d = (float)bc[k];
      sp[k] += wd * a + ws * b;
      qp[k] += wd * a * a + ws * b * b;
      sc[k] += ws * c + wd * d;
      qc[k] += ws * c * c + wd * d * d;
    }
  }
#pragma unroll
  for (int k = 0; k < 4; ++k) {
    sp[k] += __shfl_xor(sp[k], 16); sp[k] += __shfl_xor(sp[k], 32);
    qp[k] += __shfl_xor(qp[k], 16); qp[k] += __shfl_xor(qp[k], 32);
    sc[k] += __shfl_xor(sc[k], 16); sc[k] += __shfl_xor(sc[k], 32);
    qc[k] += __shfl_xor(qc[k], 16); qc[k] += __shfl_xor(qc[k], 32);
  }
  if (lane < 16) {
#pragma unroll
    for (int k = 0; k < 4; ++k) {
      atomicAdd(&sacc[4 * q + k], sp[k]);
      atomicAdd(&sacc[64 + 4 * q + k], qp[k]);
      atomicAdd(&sacc[128 + 4 * q + k], sc[k]);
      atomicAdd(&sacc[192 + 4 * q + k], qc[k]);
    }
  }
  __syncthreads();
  for (int t = threadIdx.x; t < 256; t += blockDim.x) {
    int dstoff = (t < 128) ? t : ST_AGG + (t - 128); // SUM1/SQ1 contiguous per agg
    atomicAdd(&stats[dstoff], sacc[t]);
  }
}

// KC: cross terms sum_e Ap[dst]*Bp[src] and sum_e Ac[src]*Bc[dst], per column.
__global__ void __launch_bounds__(256) k_cross(
    const int* __restrict__ src, const int* __restrict__ dst,
    const __bf16* __restrict__ Ap, const __bf16* __restrict__ Bp,
    const __bf16* __restrict__ Ac, const __bf16* __restrict__ Bc,
    float* __restrict__ stats) {
  const int lane = threadIdx.x & 63;
  const int g = lane >> 4, q = lane & 15;
  __shared__ float sacc[128];
  for (int t = threadIdx.x; t < 128; t += blockDim.x) sacc[t] = 0.f;
  __syncthreads();
  float cp[4] = {0, 0, 0, 0}, cc[4] = {0, 0, 0, 0};
  int wgid = (blockIdx.x * blockDim.x + threadIdx.x) >> 6;
  int nw = (gridDim.x * blockDim.x) >> 6;
  for (int ch = wgid; ch < NE / 64; ch += nw) {
    int e0 = ch * 64;
    int s64 = src[e0 + lane];
    int d64 = dst[e0 + lane];
#pragma unroll 4
    for (int t = 0; t < 16; ++t) {
      int u = t * 4 + g;
      int s = __shfl(s64, u);
      int d = __shfl(d64, u);
      bf16x4 ap = *(const bf16x4*)(Ap + d * 64 + 4 * q);
      bf16x4 bp = *(const bf16x4*)(Bp + s * 64 + 4 * q);
      bf16x4 ac = *(const bf16x4*)(Ac + s * 64 + 4 * q);
      bf16x4 bc = *(const bf16x4*)(Bc + d * 64 + 4 * q);
#pragma unroll
      for (int k = 0; k < 4; ++k) {
        cp[k] += (float)ap[k] * (float)bp[k];
        cc[k] += (float)ac[k] * (float)bc[k];
      }
    }
  }
#pragma unroll
  for (int k = 0; k < 4; ++k) {
    cp[k] += __shfl_xor(cp[k], 16); cp[k] += __shfl_xor(cp[k], 32);
    cc[k] += __shfl_xor(cc[k], 16); cc[k] += __shfl_xor(cc[k], 32);
  }
  if (lane < 16) {
#pragma unroll
    for (int k = 0; k < 4; ++k) {
      atomicAdd(&sacc[4 * q + k], cp[k]);
      atomicAdd(&sacc[64 + 4 * q + k], cc[k]);
    }
  }
  __syncthreads();
  for (int t = threadIdx.x; t < 128; t += blockDim.x) {
    int dstoff = (t < 64) ? (ST_CROSS + t) : (ST_AGG + ST_CROSS + (t - 64));
    atomicAdd(&stats[dstoff], sacc[t]);
  }
}

// KD: BN2 stats for BOTH aggregations in one edge pass, no h2 store.
// v = relu(bn1(A[i]+B[j])); h2 = v@W2; accumulate sum(h2), sum(h2^2).
__global__ void __launch_bounds__(256) k_edge_stats2(
    const int* __restrict__ src, const int* __restrict__ dst,
    const __bf16* __restrict__ Ap, const __bf16* __restrict__ Bp,
    const __bf16* __restrict__ Ac, const __bf16* __restrict__ Bc,
    const float* __restrict__ pg1, const float* __restrict__ pbe1,
    const float* __restrict__ cg1, const float* __restrict__ cbe1,
    const float* __restrict__ pW2, const float* __restrict__ cW2,
    float* __restrict__ stats) {
  const int lane = threadIdx.x & 63;
  const int wid = threadIdx.x >> 6;
  const int g = lane >> 4, q = lane & 15;
  __shared__ alignas(16) __bf16 vbuf[4][2][16 * 72];
  __shared__ float sred[256];
  float s1p[4], t1p[4], s1c[4], t1c[4];
#pragma unroll
  for (int k = 0; k < 4; ++k) {
    int c = 4 * q + k;
    float mu = stats[ST_SUM1 + c] * (1.f / NE);
    float var = (stats[ST_SQ1 + c] + 2.f * stats[ST_CROSS + c]) * (1.f / NE) - mu * mu;
    float s = pg1[c] * rsqrtf(var + BN_EPS);
    s1p[k] = s;
    t1p[k] = pbe1[c] - mu * s;
    mu = stats[ST_AGG + ST_SUM1 + c] * (1.f / NE);
    var = (stats[ST_AGG + ST_SQ1 + c] + 2.f * stats[ST_AGG + ST_CROSS + c]) * (1.f / NE) - mu * mu;
    s = cg1[c] * rsqrtf(var + BN_EPS);
    s1c[k] = s;
    t1c[k] = cbe1[c] - mu * s;
  }
  bf16x8 wfp[4][2], wfc[4][2];
#pragma unroll
  for (int ct = 0; ct < 4; ++ct)
#pragma unroll
    for (int kb = 0; kb < 2; ++kb) {
      wfp[ct][kb] = load_wfrag(pW2, 64, kb, ct, lane);
      wfc[ct][kb] = load_wfrag(cW2, 64, kb, ct, lane);
    }
  float sump[4] = {0, 0, 0, 0}, ssqp[4] = {0, 0, 0, 0};
  float sumc[4] = {0, 0, 0, 0}, ssqc[4] = {0, 0, 0, 0};
  __bf16* vbp = vbuf[wid][0];
  __bf16* vbc = vbuf[wid][1];
  int wgid = (blockIdx.x * blockDim.x + threadIdx.x) >> 6;
  int nw = (gridDim.x * blockDim.x) >> 6;
  for (int tile = wgid; tile < NE / 16; tile += nw) {
    int e0 = tile * 16;
    int s16 = src[e0 + q];
    int d16 = dst[e0 + q];
#pragma unroll
    for (int t = 0; t < 4; ++t) {
      int et = t * 4 + g;
      int s = __shfl(s16, et);
      int d = __shfl(d16, et);
      bf16x4 ap = *(const bf16x4*)(Ap + (size_t)d * 64 + 4 * q);
      bf16x4 bp = *(const bf16x4*)(Bp + (size_t)s * 64 + 4 * q);
      bf16x4 ac = *(const bf16x4*)(Ac + (size_t)s * 64 + 4 * q);
      bf16x4 bc = *(const bf16x4*)(Bc + (size_t)d * 64 + 4 * q);
      bf16x4 vp4, vc4;
#pragma unroll
      for (int k = 0; k < 4; ++k) {
        vp4[k] = (__bf16)fmaxf(s1p[k] * ((float)ap[k] + (float)bp[k]) + t1p[k], 0.f);
        vc4[k] = (__bf16)fmaxf(s1c[k] * ((float)ac[k] + (float)bc[k]) + t1c[k], 0.f);
      }
      *(bf16x4*)&vbp[et * 72 + 4 * q] = vp4;
      *(bf16x4*)&vbc[et * 72 + 4 * q] = vc4;
    }
    const bf16x8 a0p = *(const bf16x8*)&vbp[q * 72 + g * 8];
    const bf16x8 a1p = *(const bf16x8*)&vbp[q * 72 + 32 + g * 8];
    const bf16x8 a0c = *(const bf16x8*)&vbc[q * 72 + g * 8];
    const bf16x8 a1c = *(const bf16x8*)&vbc[q * 72 + 32 + g * 8];
#pragma unroll
    for (int ct = 0; ct < 4; ++ct) {
      floatx4 accp = {0.f, 0.f, 0.f, 0.f}, accc = {0.f, 0.f, 0.f, 0.f};
      accp = MFMA16(a0p, wfp[ct][0], accp);
      accp = MFMA16(a1p, wfp[ct][1], accp);
      accc = MFMA16(a0c, wfc[ct][0], accc);
      accc = MFMA16(a1c, wfc[ct][1], accc);
#pragma unroll
      for (int r = 0; r < 4; ++r) {
        float hp = accp[r], hc = accc[r];
        sump[ct] += hp;
        ssqp[ct] += hp * hp;
        sumc[ct] += hc;
        ssqc[ct] += hc * hc;
      }
    }
  }
  for (int t = threadIdx.x; t < 256; t += blockDim.x) sred[t] = 0.f;
  __syncthreads();
#pragma unroll
  for (int ct = 0; ct < 4; ++ct) {
    atomicAdd(&sred[ct * 16 + q], sump[ct]);
    atomicAdd(&sred[64 + ct * 16 + q], ssqp[ct]);
    atomicAdd(&sred[128 + ct * 16 + q], sumc[ct]);
    atomicAdd(&sred[192 + ct * 16 + q], ssqc[ct]);
  }
  __syncthreads();
  for (int t = threadIdx.x; t < 256; t += blockDim.x) {
    int dstoff;
    if (t < 64) dstoff = ST_SUM2 + t;
    else if (t < 128) dstoff = ST_SSQ2 + (t - 64);
    else if (t < 192) dstoff = ST_AGG + ST_SUM2 + (t - 128);
    else dstoff = ST_AGG + ST_SSQ2 + (t - 192);
    atomicAdd(&stats[dstoff], sred[t]);
  }
}

// KE: fused edge-MLP + segmented scatter: one wave per node; recompute
// v -> h2 via MFMA over 16-edge tiles of the node's CSR range; relu(bn2),
// masked ragged rows; degree-normalized output. No h2 materialization.
__global__ void __launch_bounds__(256) k_scatter_fused(
    const int* __restrict__ off, const float* __restrict__ dinv,
    const int* __restrict__ jl, const __bf16* __restrict__ A_,
    const __bf16* __restrict__ B_, const float* __restrict__ g1,
    const float* __restrict__ be1, const float* __restrict__ g2,
    const float* __restrict__ be2, const float* __restrict__ W2,
    const float* __restrict__ stats, int sbase, float* __restrict__ outb) {
  const int lane = threadIdx.x & 63;
  const int wid = threadIdx.x >> 6;
  const int g = lane >> 4, q = lane & 15;
  __shared__ alignas(16) __bf16 vbuf[4][16 * 72];
  float s1v[4], t1v[4];
#pragma unroll
  for (int k = 0; k < 4; ++k) {
    int c = 4 * q + k;
    float mu = stats[sbase + ST_SUM1 + c] * (1.f / NE);
    float var = (stats[sbase + ST_SQ1 + c] + 2.f * stats[sbase + ST_CROSS + c]) * (1.f / NE) - mu * mu;
    float s = g1[c] * rsqrtf(var + BN_EPS);
    s1v[k] = s;
    t1v[k] = be1[c] - mu * s;
  }
  float s2v[4], t2v[4];
#pragma unroll
  for (int ct = 0; ct < 4; ++ct) {
    int c = ct * 16 + q;
    float mu = stats[sbase + ST_SUM2 + c] * (1.f / NE);
    float var = stats[sbase + ST_SSQ2 + c] * (1.f / NE) - mu * mu;
    float s = g2[c] * rsqrtf(var + BN_EPS);
    s2v[ct] = s;
    t2v[ct] = be2[c] - mu * s;
  }
  bf16x8 wf[4][2];
#pragma unroll
  for (int ct = 0; ct < 4; ++ct)
#pragma unroll
    for (int kb = 0; kb < 2; ++kb) wf[ct][kb] = load_wfrag(W2, 64, kb, ct, lane);
  __bf16* vb = vbuf[wid];
  int wgid = (blockIdx.x * blockDim.x + threadIdx.x) >> 6;
  int nw = (gridDim.x * blockDim.x) >> 6;
  for (int n = wgid; n < NN; n += nw) {
    int p0 = off[n], p1 = off[n + 1];
    bf16x4 a4 = *(const bf16x4*)(A_ + (size_t)n * 64 + 4 * q);
    float ha[4];
#pragma unroll
    for (int k = 0; k < 4; ++k) ha[k] = (float)a4[k];
    float oacc[4] = {0.f, 0.f, 0.f, 0.f};
    for (int pt = p0; pt < p1; pt += 16) {
      int m = p1 - pt;
      if (m > 16) m = 16;
      int jj = (lane < m) ? jl[pt + lane] : 0;
#pragma unroll
      for (int t = 0; t < 4; ++t) {
        int et = t * 4 + g;
        int j = __shfl(jj, et);
        bf16x4 b4 = *(const bf16x4*)(B_ + (size_t)j * 64 + 4 * q);
        bf16x4 v4;
#pragma unroll
        for (int k = 0; k < 4; ++k)
          v4[k] = (__bf16)fmaxf(s1v[k] * (ha[k] + (float)b4[k]) + t1v[k], 0.f);
        *(bf16x4*)&vb[et * 72 + 4 * q] = v4;
      }
      const bf16x8 a0 = *(const bf16x8*)&vb[q * 72 + g * 8];
      const bf16x8 a1 = *(const bf16x8*)&vb[q * 72 + 32 + g * 8];
#pragma unroll
      for (int ct = 0; ct < 4; ++ct) {
        floatx4 acc = {0.f, 0.f, 0.f, 0.f};
        acc = MFMA16(a0, wf[ct][0], acc);
        acc = MFMA16(a1, wf[ct][1], acc);
#pragma unroll
        for (int r = 0; r < 4; ++r)
          if (g * 4 + r < m) oacc[ct] += fmaxf(s2v[ct] * acc[r] + t2v[ct], 0.f);
      }
    }
#pragma unroll
    for (int ct = 0; ct < 4; ++ct) {
      oacc[ct] += __shfl_xor(oacc[ct], 16);
      oacc[ct] += __shfl_xor(oacc[ct], 32);
    }
    float val = (g == 0) ? oacc[0] : (g == 1) ? oacc[1] : (g == 2) ? oacc[2] : oacc[3];
    outb[(size_t)n * 64 + lane] = dinv[n] * val; // col = g*16+q = lane
  }
}

// KF: fused node update: upd = relu([x|fi|fo]@fcW + fcb)@fc2W + fc2b ; x += upd.
__global__ void __launch_bounds__(256) k_node_update(
    float* __restrict__ x, const float* __restrict__ fi, const float* __restrict__ fo,
    const float* __restrict__ fcW, const float* __restrict__ fcb,
    const float* __restrict__ fc2W, const float* __restrict__ fc2b) {
  const int lane = threadIdx.x & 63;
  const int wid = threadIdx.x >> 6;
  __shared__ alignas(16) __bf16 cat[16 * 200];
  __shared__ alignas(16) __bf16 v2[16 * 136];
  bf16x8 wf1[2][6];
#pragma unroll
  for (int c = 0; c < 2; ++c) {
    int ct = 2 * wid + c;
#pragma unroll
    for (int kb = 0; kb < 6; ++kb) wf1[c][kb] = load_wfrag(fcW, 128, kb, ct, lane);
  }
  bf16x8 wf2[4];
#pragma unroll
  for (int kb = 0; kb < 4; ++kb) wf2[kb] = load_wfrag(fc2W, 64, kb, wid, lane);
  float fcbv[2];
#pragma unroll
  for (int c = 0; c < 2; ++c) fcbv[c] = fcb[(2 * wid + c) * 16 + (lane & 15)];
  float fc2bv = fc2b[wid * 16 + (lane & 15)];

  for (int tile = blockIdx.x; tile < NN / 16; tile += gridDim.x) {
#pragma unroll
    for (int r = 0; r < 4; ++r) {
      int rr = wid * 4 + r;
      int n = tile * 16 + rr;
      cat[rr * 200 + lane] = (__bf16)x[n * 64 + lane];
      cat[rr * 200 + 64 + lane] = (__bf16)fi[n * 64 + lane];
      cat[rr * 200 + 128 + lane] = (__bf16)fo[n * 64 + lane];
    }
    __syncthreads();
    floatx4 acc0 = {0.f, 0.f, 0.f, 0.f}, acc1 = {0.f, 0.f, 0.f, 0.f};
#pragma unroll
    for (int kb = 0; kb < 6; ++kb) {
      bf16x8 af = *(const bf16x8*)&cat[(lane & 15) * 200 + kb * 32 + ((lane >> 4) << 3)];
      acc0 = MFMA16(af, wf1[0][kb], acc0);
      acc1 = MFMA16(af, wf1[1][kb], acc1);
    }
#pragma unroll
    for (int r = 0; r < 4; ++r) {
      int row = ((lane >> 4) << 2) + r;
      v2[row * 136 + (2 * wid) * 16 + (lane & 15)] = (__bf16)fmaxf(acc0[r] + fcbv[0], 0.f);
      v2[row * 136 + (2 * wid + 1) * 16 + (lane & 15)] = (__bf16)fmaxf(acc1[r] + fcbv[1], 0.f);
    }
    __syncthreads();
    floatx4 a2 = {0.f, 0.f, 0.f, 0.f};
#pragma unroll
    for (int kb = 0; kb < 4; ++kb) {
      bf16x8 af = *(const bf16x8*)&v2[(lane & 15) * 136 + kb * 32 + ((lane >> 4) << 3)];
      a2 = MFMA16(af, wf2[kb], a2);
    }
#pragma unroll
    for (int r = 0; r < 4; ++r) {
      int row = ((lane >> 4) << 2) + r;
      int n = tile * 16 + row;
      x[n * 64 + wid * 16 + (lane & 15)] += a2[r] + fc2bv;
    }
    __syncthreads();
  }
}

// KG: out = x@convW + convb (f32 for accuracy margin).
__global__ void __launch_bounds__(256) k_conv(const float* __restrict__ x,
                                              const float* __restrict__ convW,
                                              const float* __restrict__ convb,
                                              float* __restrict__ out) {
  const int lane = threadIdx.x & 63;
  int wgid = (blockIdx.x * blockDim.x + threadIdx.x) >> 6;
  int nw = (gridDim.x * blockDim.x) >> 6;
  int half = wgid & 1;
  int col = half * 64 + lane;
  float wreg[64];
#pragma unroll
  for (int k = 0; k < 64; ++k) wreg[k] = convW[k * 128 + col];
  float bv = convb[col];
  for (int n = (wgid >> 1); n < NN; n += (nw >> 1)) {
    float xv = x[n * 64 + lane];
    float acc = bv;
#pragma unroll
    for (int k = 0; k < 64; ++k) acc += __shfl(xv, k) * wreg[k];
    out[(size_t)n * 128 + col] = acc;
  }
}

extern "C" void kernel_launch(void* const* d_in, const int* in_sizes, int n_in,
                              void* d_out, int out_size, void* d_ws, size_t ws_size,
                              hipStream_t stream) {
  const int* nodes = (const int*)d_in[0];
  const int* edges = (const int*)d_in[1];
  const int* src = edges;      // edges[0]
  const int* dst = edges + NE; // edges[1]
  const float* emb = (const float*)d_in[2];
  const float* pW1 = (const float*)d_in[3];
  const float* pg1 = (const float*)d_in[5];
  const float* pbe1 = (const float*)d_in[6];
  const float* pW2 = (const float*)d_in[7];
  const float* pg2 = (const float*)d_in[9];
  const float* pbe2 = (const float*)d_in[10];
  const float* cW1 = (const float*)d_in[11];
  const float* cg1 = (const float*)d_in[13];
  const float* cbe1 = (const float*)d_in[14];
  const float* cW2 = (const float*)d_in[15];
  const float* cg2 = (const float*)d_in[17];
  const float* cbe2 = (const float*)d_in[18];
  const float* fcW = (const float*)d_in[19];
  const float* fcb = (const float*)d_in[20];
  const float* fc2W = (const float*)d_in[21];
  const float* fc2b = (const float*)d_in[22];
  const float* convW = (const float*)d_in[23];
  const float* convb = (const float*)d_in[24];
  float* out = (float*)d_out;

  char* w = (char*)d_ws;
  auto alloc = [&](size_t bytes) {
    char* p = w;
    w += (bytes + 255) & ~(size_t)255;
    return p;
  };
  float* x = (float*)alloc((size_t)NN * 64 * 4);
  __bf16* Ap = (__bf16*)alloc((size_t)NN * 64 * 2);
  __bf16* Bp = (__bf16*)alloc((size_t)NN * 64 * 2);
  __bf16* Ac = (__bf16*)alloc((size_t)NN * 64 * 2);
  __bf16* Bc = (__bf16*)alloc((size_t)NN * 64 * 2);
  float* fi = (float*)alloc((size_t)NN * 64 * 4);
  float* fo = (float*)alloc((size_t)NN * 64 * 4);
  int* jl_d = (int*)alloc((size_t)NE * 4);
  int* jl_s = (int*)alloc((size_t)NE * 4);
  int* off_d = (int*)alloc((size_t)(NN + 1) * 4);
  int* off_s = (int*)alloc((size_t)(NN + 1) * 4);
  int* cur_d = (int*)alloc((size_t)NN * 4);
  int* cur_s = (int*)alloc((size_t)NN * 4);
  int* cnt_d = (int*)alloc((size_t)NN * 4);
  int* cnt_s = (int*)alloc((size_t)NN * 4);
  float* dinv_d = (float*)alloc((size_t)NN * 4);
  float* dinv_s = (float*)alloc((size_t)NN * 4);
  float* stats = (float*)alloc(2 * ST_AGG * 4);
  int* btot = (int*)alloc(2 * SCAN_NB * 4);

  k_setup<<<1024, 256, 0, stream>>>(nodes, emb, x, cnt_d, cnt_s);
  k_hist<<<1024, 256, 0, stream>>>(src, dst, cnt_d, cnt_s);
  k_scan1<<<dim3(SCAN_NB, 2), SCAN_T, 0, stream>>>(cnt_d, cnt_s, off_d, off_s, btot);
  k_scan2<<<1, SCAN_T, 0, stream>>>(btot);
  k_scan3<<<dim3(SCAN_NB, 2), SCAN_T, 0, stream>>>(cnt_d, cnt_s, off_d, off_s, btot,
                                                   cur_d, cur_s, dinv_d, dinv_s);
  k_fill<<<2048, 256, 0, stream>>>(src, dst, cur_d, cur_s, jl_d, jl_s);

  for (int it = 0; it < 2; ++it) {
    k_node_xform<<<784, 256, 0, stream>>>(x, pW1, Ap, Bp, stats, 1);
    k_node_xform<<<784, 256, 0, stream>>>(x, cW1, Ac, Bc, stats, 0);
    k_node_stats<<<256, 256, 0, stream>>>(Ap, Bp, Ac, Bc, cnt_d, cnt_s, stats);
    k_cross<<<1024, 256, 0, stream>>>(src, dst, Ap, Bp, Ac, Bc, stats);
    k_edge_stats2<<<2048, 256, 0, stream>>>(src, dst, Ap, Bp, Ac, Bc, pg1, pbe1,
                                            cg1, cbe1, pW2, cW2, stats);
    // Parent: i = dst, j = src, dst-CSR -> fi
    k_scatter_fused<<<2048, 256, 0, stream>>>(off_d, dinv_d, jl_d, Ap, Bp, pg1, pbe1,
                                              pg2, pbe2, pW2, stats, 0, fi);
    // Child: i = src, j = dst, src-CSR -> fo
    k_scatter_fused<<<2048, 256, 0, stream>>>(off_s, dinv_s, jl_s, Ac, Bc, cg1, cbe1,
                                              cg2, cbe2, cW2, stats, ST_AGG, fo);
    // Node update
    k_node_update<<<3125, 256, 0, stream>>>(x, fi, fo, fcW, fcb, fc2W, fc2b);
  }
  k_conv<<<2048, 256, 0, stream>>>(x, convW, convb, out);
}